// Round 4
// baseline (36.252 us; speedup 1.0000x reference)
//
#include <hip/hip_runtime.h>
#include <hip/hip_fp16.h>

#define IN_F   4096
#define OUT_F  11008
#define BATCH  16
#define GROUPS 32                    // 4096 / 128
#define PACKED_PER_ROW (IN_F / 2)    // 2048 int32 per output row

typedef __attribute__((ext_vector_type(8))) _Float16 half8;
typedef __attribute__((ext_vector_type(4))) _Float16 half4;
typedef __attribute__((ext_vector_type(2))) _Float16 h2;
typedef __attribute__((ext_vector_type(4))) float    float4_t;
typedef __attribute__((ext_vector_type(4))) int      int4_t;
typedef __attribute__((ext_vector_type(4))) unsigned uint4_t;

__device__ inline h2 cvt2(float a, float b) {
    return __builtin_bit_cast(h2, __builtin_amdgcn_cvt_pkrtz(a, b));
}

// ---- pre-pass: x (16x4096 f32) -> f16 table in workspace (128 KB) ----
__global__ __launch_bounds__(256) void xcvt(const float* __restrict__ x,
                                            _Float16* __restrict__ xh) {
    const int i = (blockIdx.x * 256 + threadIdx.x) * 4;   // 64 blocks cover 65536
    const float4_t v = *(const float4_t*)(x + i);
    half2_t_unused: ;
    half4 h;
    h2 lo = cvt2(v.x, v.y), hi = cvt2(v.z, v.w);
    h[0] = lo[0]; h[1] = lo[1]; h[2] = hi[0]; h[3] = hi[1];
    *(half4*)(xh + i) = h;
}

// One wave computes a 16(b) x 16(o) f32 tile over a (IN_F/S/4)-col K-slice via
// mfma_f32_16x16x32_f16. Lane l loads qw[o = l&15][.. + (l>>4)*4 ..] as
// dwordx4 whose 8 nibbles are exactly the lane's 8 B-fragment elements.
// Per 256-col chunk: stage 8 qw + 8 x dwordx4 loads in registers FIRST
// (deep MLP), then dequant (packed f16 magic-number) + 8 MFMAs.
template<int S, bool XH>
__global__ __launch_bounds__(256) void gptq_gemm(
    const float* __restrict__ x, const _Float16* __restrict__ xh,
    const int* __restrict__ qw,
    const float* __restrict__ scales, const float* __restrict__ zeros,
    const float* __restrict__ bias, float* __restrict__ out,
    float* __restrict__ ws_part)
{
    const int tid  = threadIdx.x;
    const int lane = tid & 63;
    const int wave = tid >> 6;
    const int otile = blockIdx.x / S;
    const int ks    = blockIdx.x % S;

    const int ln = lane & 15;   // A-row (b) / B-col (o) index
    const int lk = lane >> 4;   // k-chunk 0..3

    const int o = otile * 16 + ln;

    constexpr int KCB = IN_F / S;    // cols per block
    constexpr int KCW = KCB / 4;     // cols per wave (S=4 -> 256)
    constexpr int NCH = KCW / 256;   // 256-col chunks (S=4 -> 1, S=1 -> 4)
    const int kc0 = ks * KCB + wave * KCW;

    const int* qbase = qw + o * PACKED_PER_ROW + (kc0 >> 1) + lk * 4;
    const float* srow = scales + o * GROUPS;
    const float* zrow = zeros  + o * GROUPS;

    float4_t acc = {0.f, 0.f, 0.f, 0.f};
    const h2 k1024 = { (_Float16)1024.0f, (_Float16)1024.0f };

    #pragma unroll
    for (int ch = 0; ch < NCH; ++ch) {
        const int cc = kc0 + ch * 256;          // chunk col base
        // group constants for the 2 groups of this chunk (lane-varying in o)
        h2 s2[2], c2[2];
        #pragma unroll
        for (int gi = 0; gi < 2; ++gi) {
            const int g = (cc >> 7) + gi;
            const float s  = srow[g];
            const float c0 = -zrow[g] * s;      // w = q*s + c0
            const _Float16 sh = (_Float16)s, chh = (_Float16)c0;
            s2[gi][0] = sh; s2[gi][1] = sh;
            c2[gi][0] = chh; c2[gi][1] = chh;
        }

        // ---- stage ALL loads of this chunk before any compute ----
        int4_t qv[8];
        #pragma unroll
        for (int t = 0; t < 8; ++t)
            qv[t] = *(const int4_t*)(qbase + ch * 128 + t * 16);

        half8 xv[8];
        #pragma unroll
        for (int t = 0; t < 8; ++t) {
            if (XH) {
                xv[t] = *(const half8*)(xh + ln * IN_F + cc + t * 32 + lk * 8);
            } else {
                const float* xp = x + ln * IN_F + cc + t * 32 + lk * 8;
                const float4_t a0 = *(const float4_t*)(xp);
                const float4_t a1 = *(const float4_t*)(xp + 4);
                h2 p0 = cvt2(a0.x, a0.y), p1 = cvt2(a0.z, a0.w);
                h2 p2 = cvt2(a1.x, a1.y), p3 = cvt2(a1.z, a1.w);
                xv[t][0]=p0[0]; xv[t][1]=p0[1]; xv[t][2]=p1[0]; xv[t][3]=p1[1];
                xv[t][4]=p2[0]; xv[t][5]=p2[1]; xv[t][6]=p3[0]; xv[t][7]=p3[1];
            }
        }

        // ---- dequant + MFMA ----
        #pragma unroll
        for (int t = 0; t < 8; ++t) {
            const int gi = t >> 2;
            uint4_t bw;
            #pragma unroll
            for (int i = 0; i < 4; ++i) {
                const unsigned pv = (unsigned)qv[t][i];
                const unsigned u = (pv & 0xFu) | ((pv << 12) & 0xF0000u)
                                 | 0x64006400u;            // {1024+qlo,1024+qhi}
                h2 q = __builtin_bit_cast(h2, u) - k1024;  // exact {qlo,qhi}
                h2 w = q * s2[gi] + c2[gi];                // packed f16 fma
                bw[i] = __builtin_bit_cast(unsigned, w);
            }
            const half8 bf = __builtin_bit_cast(half8, bw);
            acc = __builtin_amdgcn_mfma_f32_16x16x32_f16(xv[t], bf, acc, 0, 0, 0);
        }
    }

    // Block reduction: 4 waves hold partial 16x16 tiles for disjoint K-slices.
    // C/D layout (m89-verified): lane holds D[(l>>4)*4 + r][l&15].
    __shared__ float red[4][16][17];
    #pragma unroll
    for (int r = 0; r < 4; ++r) red[wave][lk * 4 + r][ln] = acc[r];
    __syncthreads();

    const int row = tid >> 4;    // b
    const int col = tid & 15;    // o within tile
    const float sum = red[0][row][col] + red[1][row][col]
                    + red[2][row][col] + red[3][row][col];
    const int oo = otile * 16 + col;
    if (S == 1) {
        out[row * OUT_F + oo] = sum + bias[oo];
    } else {
        ws_part[(ks * BATCH + row) * OUT_F + oo] = sum;
    }
}

__global__ __launch_bounds__(256) void gptq_reduce(
    const float* __restrict__ ws_part, const float* __restrict__ bias,
    float* __restrict__ out, int S)
{
    const int idx = blockIdx.x * 256 + threadIdx.x;   // b*OUT_F + o
    if (idx >= BATCH * OUT_F) return;
    const int o = idx % OUT_F;
    float sum = bias[o];
    for (int ks = 0; ks < S; ++ks)
        sum += ws_part[ks * (BATCH * OUT_F) + idx];
    out[idx] = sum;
}

extern "C" void kernel_launch(void* const* d_in, const int* in_sizes, int n_in,
                              void* d_out, int out_size, void* d_ws, size_t ws_size,
                              hipStream_t stream) {
    const float* x      = (const float*)d_in[0];
    const int*   qwgt   = (const int*)d_in[1];
    const float* scales = (const float*)d_in[2];
    const float* zeros  = (const float*)d_in[3];
    const float* bias   = (const float*)d_in[4];
    float* out = (float*)d_out;

    const int nOTiles = OUT_F / 16;                    // 688
    const size_t need = (size_t)8 << 20;               // partials + xh + slack

    if (d_ws && ws_size >= need) {
        float*    ws_part = (float*)d_ws;                         // 2.75 MB
        _Float16* xh      = (_Float16*)((char*)d_ws + (4 << 20)); // 128 KB
        constexpr int S = 4;
        hipLaunchKernelGGL(xcvt, dim3(BATCH * IN_F / 1024), dim3(256), 0, stream,
                           x, xh);
        hipLaunchKernelGGL((gptq_gemm<S, true>), dim3(nOTiles * S), dim3(256),
                           0, stream, x, xh, qwgt, scales, zeros, bias, out,
                           ws_part);
        hipLaunchKernelGGL(gptq_reduce, dim3((BATCH * OUT_F + 255) / 256),
                           dim3(256), 0, stream, ws_part, bias, out, S);
    } else {
        hipLaunchKernelGGL((gptq_gemm<1, false>), dim3(nOTiles), dim3(256),
                           0, stream, x, (const _Float16*)nullptr, qwgt,
                           scales, zeros, bias, out, (float*)nullptr);
    }
}

// Round 5
// 35.301 us; speedup vs baseline: 1.0269x; 1.0269x over previous
//
#include <hip/hip_runtime.h>
#include <hip/hip_fp16.h>

#define IN_F   4096
#define OUT_F  11008
#define BATCH  16
#define GROUPS 32                    // 4096 / 128
#define PACKED_PER_ROW (IN_F / 2)    // 2048 int32 per output row

typedef __attribute__((ext_vector_type(8))) _Float16 half8;
typedef __attribute__((ext_vector_type(4))) _Float16 half4;
typedef __attribute__((ext_vector_type(2))) _Float16 h2;
typedef __attribute__((ext_vector_type(4))) float    float4_t;
typedef __attribute__((ext_vector_type(4))) int      int4_t;
typedef __attribute__((ext_vector_type(4))) unsigned uint4_t;

__device__ inline h2 cvt2(float a, float b) {
    return __builtin_bit_cast(h2, __builtin_amdgcn_cvt_pkrtz(a, b));
}

// ---- pre-pass: x (16x4096 f32) -> f16 table in workspace (128 KB) ----
__global__ __launch_bounds__(256) void xcvt(const float* __restrict__ x,
                                            _Float16* __restrict__ xh) {
    const int i = (blockIdx.x * 256 + threadIdx.x) * 4;   // 64 blocks cover 65536
    const float4_t v = *(const float4_t*)(x + i);
    half4 h;
    h2 lo = cvt2(v.x, v.y), hi = cvt2(v.z, v.w);
    h[0] = lo[0]; h[1] = lo[1]; h[2] = hi[0]; h[3] = hi[1];
    *(half4*)(xh + i) = h;
}

// ---- main: 1 wave per block, streaming pipeline, no barriers ----
// Block (otile, kq): 16 output cols x 1024 K-cols, as 4 chunks of 256.
// Per chunk: lane l holds B-fragment = 4 packed int32 of row o=otile*16+(l&15)
// (8 nibbles = its 8 f16 elems for k-slice (l>>4)), A-fragment = 8 xh halves.
// Chunk c+1's 16 loads are issued before chunk c's dequant+MFMA -> the wave
// keeps ~8-16 KB of HBM traffic outstanding for most of its life.
__global__ __launch_bounds__(64) void gptq_gemm_w(
    const _Float16* __restrict__ xh, const int* __restrict__ qw,
    const float* __restrict__ scales, const float* __restrict__ zeros,
    float* __restrict__ ws_part)
{
    const int lane  = threadIdx.x;       // 0..63
    const int otile = blockIdx.x >> 2;
    const int kq    = blockIdx.x & 3;

    const int ln = lane & 15;            // o within tile / x row select
    const int lk = lane >> 4;            // k-subchunk 0..3
    const int o  = otile * 16 + ln;

    const int*      qbase = qw + o * PACKED_PER_ROW + kq * 512 + lk * 4;
    const _Float16* xbase = xh + ln * IN_F + kq * 1024 + lk * 8;

    // 8 group scales/zeros for this quarter: 4 vector loads
    const float4_t sf0 = *(const float4_t*)(scales + o * GROUPS + kq * 8);
    const float4_t sf1 = *(const float4_t*)(scales + o * GROUPS + kq * 8 + 4);
    const float4_t zf0 = *(const float4_t*)(zeros  + o * GROUPS + kq * 8);
    const float4_t zf1 = *(const float4_t*)(zeros  + o * GROUPS + kq * 8 + 4);
    const float sArr[8] = { sf0.x, sf0.y, sf0.z, sf0.w, sf1.x, sf1.y, sf1.z, sf1.w };
    const float zArr[8] = { zf0.x, zf0.y, zf0.z, zf0.w, zf1.x, zf1.y, zf1.z, zf1.w };

    int4_t qv[2][8];
    half8  xv[2][8];

    #pragma unroll
    for (int t = 0; t < 8; ++t) {
        qv[0][t] = *(const int4_t*)(qbase + t * 16);
        xv[0][t] = *(const half8*)(xbase + t * 32);
    }

    float4_t acc = {0.f, 0.f, 0.f, 0.f};
    const h2 k1024 = { (_Float16)1024.0f, (_Float16)1024.0f };

    #pragma unroll
    for (int c = 0; c < 4; ++c) {
        const int cur = c & 1, nxt = cur ^ 1;   // compile-time after unroll
        if (c < 3) {
            #pragma unroll
            for (int t = 0; t < 8; ++t) {
                qv[nxt][t] = *(const int4_t*)(qbase + (c + 1) * 128 + t * 16);
                xv[nxt][t] = *(const half8*)(xbase + (c + 1) * 256 + t * 32);
            }
        }
        // per-group packed constants: w = q*s + (-z*s)
        h2 s2[2], c2[2];
        #pragma unroll
        for (int gi = 0; gi < 2; ++gi) {
            const float s  = sArr[2 * c + gi];
            const float c0 = -zArr[2 * c + gi] * s;
            s2[gi] = cvt2(s, s);
            c2[gi] = cvt2(c0, c0);
        }
        #pragma unroll
        for (int t = 0; t < 8; ++t) {
            const int gi = t >> 2;
            uint4_t bw;
            #pragma unroll
            for (int i = 0; i < 4; ++i) {
                const unsigned pv = (unsigned)qv[cur][t][i];
                const unsigned u = (pv & 0xFu) | ((pv << 12) & 0xF0000u)
                                 | 0x64006400u;            // {1024+qlo,1024+qhi}
                h2 q = __builtin_bit_cast(h2, u) - k1024;  // exact {qlo,qhi}
                h2 w = q * s2[gi] + c2[gi];                // v_pk_fma_f16
                bw[i] = __builtin_bit_cast(unsigned, w);
            }
            acc = __builtin_amdgcn_mfma_f32_16x16x32_f16(
                xv[cur][t], __builtin_bit_cast(half8, bw), acc, 0, 0, 0);
        }
    }

    // C/D layout (verified): lane holds D[row=(l>>4)*4+r][col=l&15], row=b, col=o
    #pragma unroll
    for (int r = 0; r < 4; ++r)
        ws_part[(kq * BATCH + lk * 4 + r) * OUT_F + otile * 16 + ln] = acc[r];
}

__global__ __launch_bounds__(256) void gptq_reduce(
    const float* __restrict__ ws_part, const float* __restrict__ bias,
    float* __restrict__ out)
{
    const int idx = blockIdx.x * 256 + threadIdx.x;   // b*OUT_F + o
    if (idx >= BATCH * OUT_F) return;
    const int o = idx % OUT_F;
    out[idx] = bias[o]
             + ws_part[idx]
             + ws_part[1 * (BATCH * OUT_F) + idx]
             + ws_part[2 * (BATCH * OUT_F) + idx]
             + ws_part[3 * (BATCH * OUT_F) + idx];
}

// ---- fallback (no workspace): old 4-wave single-pass kernel, S=1 ----
__global__ __launch_bounds__(256) void gptq_gemm_fb(
    const float* __restrict__ x, const int* __restrict__ qw,
    const float* __restrict__ scales, const float* __restrict__ zeros,
    const float* __restrict__ bias, float* __restrict__ out)
{
    const int tid  = threadIdx.x;
    const int lane = tid & 63;
    const int wave = tid >> 6;
    const int otile = blockIdx.x;
    const int ln = lane & 15, lk = lane >> 4;
    const int o = otile * 16 + ln;
    const int kc0 = wave * 1024;

    const int* qbase = qw + o * PACKED_PER_ROW + (kc0 >> 1) + lk * 4;
    const float* srow = scales + o * GROUPS;
    const float* zrow = zeros  + o * GROUPS;

    float4_t acc = {0.f, 0.f, 0.f, 0.f};
    const h2 k1024 = { (_Float16)1024.0f, (_Float16)1024.0f };

    #pragma unroll
    for (int ch = 0; ch < 4; ++ch) {
        const int cc = kc0 + ch * 256;
        h2 s2[2], c2[2];
        #pragma unroll
        for (int gi = 0; gi < 2; ++gi) {
            const float s  = srow[(cc >> 7) + gi];
            const float c0 = -zrow[(cc >> 7) + gi] * s;
            s2[gi] = cvt2(s, s); c2[gi] = cvt2(c0, c0);
        }
        #pragma unroll
        for (int t = 0; t < 8; ++t) {
            const int4_t v = *(const int4_t*)(qbase + ch * 128 + t * 16);
            const float* xp = x + ln * IN_F + cc + t * 32 + lk * 8;
            const float4_t a0 = *(const float4_t*)(xp);
            const float4_t a1 = *(const float4_t*)(xp + 4);
            half8 af;
            h2 p0 = cvt2(a0.x, a0.y), p1 = cvt2(a0.z, a0.w);
            h2 p2 = cvt2(a1.x, a1.y), p3 = cvt2(a1.z, a1.w);
            af[0]=p0[0]; af[1]=p0[1]; af[2]=p1[0]; af[3]=p1[1];
            af[4]=p2[0]; af[5]=p2[1]; af[6]=p3[0]; af[7]=p3[1];
            const int gi = t >> 2;
            uint4_t bw;
            #pragma unroll
            for (int i = 0; i < 4; ++i) {
                const unsigned pv = (unsigned)v[i];
                const unsigned u = (pv & 0xFu) | ((pv << 12) & 0xF0000u)
                                 | 0x64006400u;
                h2 q = __builtin_bit_cast(h2, u) - k1024;
                h2 w = q * s2[gi] + c2[gi];
                bw[i] = __builtin_bit_cast(unsigned, w);
            }
            acc = __builtin_amdgcn_mfma_f32_16x16x32_f16(
                af, __builtin_bit_cast(half8, bw), acc, 0, 0, 0);
        }
    }

    __shared__ float red[4][16][17];
    #pragma unroll
    for (int r = 0; r < 4; ++r) red[wave][lk * 4 + r][ln] = acc[r];
    __syncthreads();
    const int row = tid >> 4, col = tid & 15;
    const float sum = red[0][row][col] + red[1][row][col]
                    + red[2][row][col] + red[3][row][col];
    const int oo = otile * 16 + col;
    out[row * OUT_F + oo] = sum + bias[oo];
}

extern "C" void kernel_launch(void* const* d_in, const int* in_sizes, int n_in,
                              void* d_out, int out_size, void* d_ws, size_t ws_size,
                              hipStream_t stream) {
    const float* x      = (const float*)d_in[0];
    const int*   qwgt   = (const int*)d_in[1];
    const float* scales = (const float*)d_in[2];
    const float* zeros  = (const float*)d_in[3];
    const float* bias   = (const float*)d_in[4];
    float* out = (float*)d_out;

    const int nOTiles = OUT_F / 16;                    // 688
    const size_t need = (size_t)8 << 20;

    if (d_ws && ws_size >= need) {
        float*    ws_part = (float*)d_ws;                         // 2.75 MB
        _Float16* xh      = (_Float16*)((char*)d_ws + (4 << 20)); // 128 KB
        hipLaunchKernelGGL(xcvt, dim3(BATCH * IN_F / 1024), dim3(256), 0, stream,
                           x, xh);
        hipLaunchKernelGGL(gptq_gemm_w, dim3(nOTiles * 4), dim3(64), 0, stream,
                           xh, qwgt, scales, zeros, ws_part);
        hipLaunchKernelGGL(gptq_reduce, dim3((BATCH * OUT_F + 255) / 256),
                           dim3(256), 0, stream, ws_part, bias, out);
    } else {
        hipLaunchKernelGGL(gptq_gemm_fb, dim3(nOTiles), dim3(256), 0, stream,
                           x, qwgt, scales, zeros, bias, out);
    }
}